// Round 1
// 90.914 us; speedup vs baseline: 1.0214x; 1.0214x over previous
//
#include <hip/hip_runtime.h>
#include <hip/hip_bf16.h>
#include <stdint.h>

#define BATCH 2
#define NPTS  2048
#define CIN   64
#define COUT  64
#define NCELL 9

// knorm = 315 / (64*pi*0.1^9)  -- folded into dC at prep time
#define KNORM 1.5666851e9f
#define R2 0.01f

typedef __attribute__((ext_vector_type(8))) __bf16 bf16x8;
typedef __attribute__((ext_vector_type(4))) float  f32x4;

union B8 { uint4 u; bf16x8 v; };

typedef __attribute__((address_space(3))) uint8_t        lds_t;
typedef const __attribute__((address_space(1))) uint8_t  glb_t;

static __device__ __forceinline__ unsigned pk2(float a, float b) {
    union { __hip_bfloat162 h; unsigned u; } cv;
    cv.h = __float22bfloat162_rn(make_float2(a, b));
    return cv.u;
}

// ---------------------------------------------------------------------------
// Workspace:
//   posT  float2[B*N]                    32 KB
//   dC    bf16  [B][C][N]  (c-major)    512 KB   -- scaled by KNORM
//   WB    bf16  [9][2ks][4ob][64][8]     72 KB   -- GEMM2 B pre-swizzled frags
// ---------------------------------------------------------------------------

__global__ __launch_bounds__(256) void prep_kernel(
    const float* __restrict__ locs, const float* __restrict__ data,
    const float* __restrict__ density, const float* __restrict__ weight,
    const float* __restrict__ bias,
    float2* __restrict__ posT, uint16_t* __restrict__ dC,
    uint16_t* __restrict__ WB, float* __restrict__ out)
{
    const int tid = threadIdx.x;
    const int g = blockIdx.x;
    if (g < 256) {
        // dC[b][c][j] = bf16( KNORM * data / (invmass * density) )
        int e = g * 256 + tid;             // 4 j each
        int j4 = e & 511, bc = e >> 9;
        int b = bc >> 6;
        float4 dv = *(const float4*)(data + bc * 2048 + j4 * 4);
        float4 de = *(const float4*)(density + b * 2048 + j4 * 4);
        int jb = (b * 2048 + j4 * 4) * 3 + 2;
        float m0 = locs[jb], m1 = locs[jb + 3], m2 = locs[jb + 6], m3 = locs[jb + 9];
        float v0 = dv.x / (m0 * de.x) * KNORM;
        float v1 = dv.y / (m1 * de.y) * KNORM;
        float v2 = dv.z / (m2 * de.z) * KNORM;
        float v3 = dv.w / (m3 * de.w) * KNORM;
        *(uint2*)(dC + bc * 2048 + j4 * 4) = make_uint2(pk2(v0, v1), pk2(v2, v3));
    } else if (g < 272) {
        int jj = (g - 256) * 256 + tid;
        posT[jj] = make_float2(locs[jj * 3], locs[jj * 3 + 1]);
    } else if (g < 272 + NCELL) {
        // WB[cell][ks][ob][lane][jj]: o = ob*16 + (lane&15), c = ks*32 + quad*8 + jj
        int cell = g - 272;
        for (int it = 0; it < 16; it++) {
            int e = it * 256 + tid;
            int ks = e >> 11, ob = (e >> 9) & 3, lane = (e >> 3) & 63, jj = e & 7;
            int o = ob * 16 + (lane & 15);
            int c = ks * 32 + ((lane >> 4) & 3) * 8 + jj;
            union { __hip_bfloat16 h; uint16_t u; } cv;
            cv.h = __float2bfloat16(weight[(o * 64 + c) * 9 + cell]);
            WB[cell * 4096 + e] = cv.u;
        }
    } else {
        // out[b][o][i] = bias[o]  (atomic accumulation target)
        const int gb = g - (272 + NCELL);
#pragma unroll
        for (int r = 0; r < 2; r++) {
            int e4 = (gb * 512 + r * 256 + tid) * 4;
            float bv = bias[(e4 >> 11) & 63];
            *(float4*)(out + e4) = make_float4(bv, bv, bv, bv);
        }
    }
}

// ---------------------------------------------------------------------------
// Fused conv, j-split x4: block = 16-i tile x 512-j range (16 chunks of 32 j).
// GEMM1: w in A-frag registers (m=lane&15=i, k=quad*8+jj=j), dcoef B-frags
// from LDS (global_load_lds staged, unpadded - DMA layout == read layout).
// Cells split 3/2/2/2 over 4 waves, heavy wave ROTATED per block so SIMD0
// doesn't systematically carry the 3-cell wave (VALU-issue balance).
// w-compute uses shared s = R2-dx^2-dy^2 + per-cell linear form (6 ops/pair
// vs 8), KNORM pre-folded into dC. GEMM2 per-wave on its own cells via a
// private LDS transpose slice; block-reduce + fp32 atomics into out.
// ---------------------------------------------------------------------------
__global__ __launch_bounds__(256, 4) void conv_kernel(
    const float2* __restrict__ posT, const uint16_t* __restrict__ dC,
    const uint16_t* __restrict__ WB, float* __restrict__ out)
{
    __shared__ uint16_t db[2][2048];          // 2 x 4KB: [c][32j] bf16, unpadded
    __shared__ float    sft[4 * 16 * 68];     // per-wave transpose/reduce slices

    const int tid  = threadIdx.x;
    const int lane = tid & 63;
    const int wid  = tid >> 6;
    const int cl   = lane & 15;
    const int quad = lane >> 4;
    const int bx   = blockIdx.x;
    const int b    = bx >> 9;
    const int i0   = ((bx >> 2) & 127) * 16;
    const int jh   = bx & 3;                  // j-range [jh*512, jh*512+512)
    const int jb0  = jh * 512;

    // cells per wave-rank: r0:{0,1,2} r1:{3,4} r2:{5,6} r3:{7,8}
    // heavy rank rotated per block: key distinct for co-resident blocks under
    // both consecutive and stride-256 round-robin dispatch.
    const int hw = ((bx >> 8) + bx) & 3;
    const int r  = (wid - hw) & 3;
    const int c0 = (r == 0) ? 0 : (1 + r * 2);
    const int nc = (r == 0) ? 3 : 2;

    // per-cell linear-form constants: t = s + cx*dx + cy*dy + cc,
    // s = R2 - dx^2 - dy^2 shared across cells
    float cxr[3], cyr[3], ccr[3];
#pragma unroll
    for (int ci = 0; ci < 3; ci++) {
        int k = c0 + (ci < nc ? ci : 0);
        float ox = (float)(k / 3 - 1) * 0.05f;
        float oy = (float)(k % 3 - 1) * 0.05f;
        cxr[ci] = -2.0f * ox;
        cyr[ci] = -2.0f * oy;
        ccr[ci] = -(ox * ox + oy * oy);
    }

    const float2 pI = posT[b * 2048 + i0 + cl];

    f32x4 acc[3][4];
#pragma unroll
    for (int ci = 0; ci < 3; ci++)
#pragma unroll
        for (int nb = 0; nb < 4; nb++) acc[ci][nb] = (f32x4){0.f, 0.f, 0.f, 0.f};

    // staging: one global_load_lds(16B) per thread per chunk
    const uint16_t* srcbase =
        dC + (b * 64 + wid * 16 + (lane >> 2)) * 2048 + jb0 + (lane & 3) * 8;

#define STAGE(n, buf)                                                         \
    __builtin_amdgcn_global_load_lds((glb_t*)(srcbase + (n) * 32),            \
                                     (lds_t*)(&db[buf][wid * 512]), 16, 0, 0)

    STAGE(0, 0);

    for (int n = 0; n < 16; n++) {
        __syncthreads();                      // chunk n staged (vmcnt drained)
        if (n < 15) STAGE(n + 1, (n + 1) & 1);
        const int buf = n & 1;

        // B-frags: dcoef[j=quad*8..+7][c=nb*16+cl]
        B8 bf[4];
#pragma unroll
        for (int nb = 0; nb < 4; nb++)
            bf[nb].u = *(const uint4*)&db[buf][(nb * 16 + cl) * 32 + quad * 8];

        // my 8 pair geometries (pj from L1-hot posT)
        const float4* pp = (const float4*)(posT + b * 2048 + jb0 + n * 32 + quad * 8);
        float4 q0 = pp[0], q1 = pp[1], q2 = pp[2], q3 = pp[3];
        float dxv[8], dyv[8], sv[8];
        dxv[0] = pI.x - q0.x; dyv[0] = pI.y - q0.y;
        dxv[1] = pI.x - q0.z; dyv[1] = pI.y - q0.w;
        dxv[2] = pI.x - q1.x; dyv[2] = pI.y - q1.y;
        dxv[3] = pI.x - q1.z; dyv[3] = pI.y - q1.w;
        dxv[4] = pI.x - q2.x; dyv[4] = pI.y - q2.y;
        dxv[5] = pI.x - q2.z; dyv[5] = pI.y - q2.w;
        dxv[6] = pI.x - q3.x; dyv[6] = pI.y - q3.y;
        dxv[7] = pI.x - q3.z; dyv[7] = pI.y - q3.w;
#pragma unroll
        for (int p = 0; p < 8; p++)
            sv[p] = fmaf(-dyv[p], dyv[p], fmaf(-dxv[p], dxv[p], R2));

#pragma unroll
        for (int ci = 0; ci < 3; ci++) {
            if (ci < nc) {                    // wave-uniform
                const float cx = cxr[ci], cy = cyr[ci], cc = ccr[ci];
                float w[8];
#pragma unroll
                for (int p = 0; p < 8; p++) {
                    float t  = fmaf(cx, dxv[p], fmaf(cy, dyv[p], sv[p] + cc));
                    float mt = fmaxf(t, 0.0f);
                    w[p] = (mt * mt) * mt;    // KNORM folded into dC
                }
                B8 af;
                af.u = make_uint4(pk2(w[0], w[1]), pk2(w[2], w[3]),
                                  pk2(w[4], w[5]), pk2(w[6], w[7]));
#pragma unroll
                for (int nb = 0; nb < 4; nb++)
                    acc[ci][nb] = __builtin_amdgcn_mfma_f32_16x16x32_bf16(
                        af.v, bf[nb].v, acc[ci][nb], 0, 0, 0);
            }
        }
    }

    // ---- GEMM2 per wave: out16x64 partial = sum_{own cells} field_k . W_k --
    float* scr = &sft[wid * (16 * 68)];
    f32x4 acc2[4];
#pragma unroll
    for (int ob = 0; ob < 4; ob++) acc2[ob] = (f32x4){0.f, 0.f, 0.f, 0.f};

#pragma unroll
    for (int ci = 0; ci < 3; ci++) {
        if (ci < nc) {
            // C-frag (row=i=quad*4+r, col=c=nb*16+cl) -> scr[i][c]
#pragma unroll
            for (int nb = 0; nb < 4; nb++)
#pragma unroll
                for (int rr = 0; rr < 4; rr++)
                    scr[(quad * 4 + rr) * 68 + nb * 16 + cl] = acc[ci][nb][rr];
            // A-frags (m=i=cl, k=c=quad*8+jj) + WB B-frags
            int k = c0 + ci;
#pragma unroll
            for (int ks = 0; ks < 2; ks++) {
                const float* fp = &scr[cl * 68 + ks * 32 + quad * 8];
                float4 lo = *(const float4*)fp;
                float4 hi = *(const float4*)(fp + 4);
                B8 af;
                af.u = make_uint4(pk2(lo.x, lo.y), pk2(lo.z, lo.w),
                                  pk2(hi.x, hi.y), pk2(hi.z, hi.w));
#pragma unroll
                for (int ob = 0; ob < 4; ob++) {
                    B8 wf;
                    wf.u = *(const uint4*)(WB + k * 4096 + (ks * 4 + ob) * 512 + lane * 8);
                    acc2[ob] = __builtin_amdgcn_mfma_f32_16x16x32_bf16(
                        af.v, wf.v, acc2[ob], 0, 0, 0);
                }
            }
        }
    }

    __syncthreads();    // everyone done with transpose use of sft
    // acc2 C-frag (row=i=quad*4+r, col=o'=cl; o=ob*16+cl) -> scr[i][o]
#pragma unroll
    for (int ob = 0; ob < 4; ob++)
#pragma unroll
        for (int rr = 0; rr < 4; rr++)
            scr[(quad * 4 + rr) * 68 + ob * 16 + cl] = acc2[ob][rr];
    __syncthreads();

    // reduce 4 wave-slices, atomically add to out. thread = (og, i)
    {
        const int i  = tid & 15;
        const int og = tid >> 4;              // 16 groups of 4 o
        float4 s0 = *(const float4*)&sft[0 * 1088 + i * 68 + og * 4];
        float4 s1 = *(const float4*)&sft[1 * 1088 + i * 68 + og * 4];
        float4 s2 = *(const float4*)&sft[2 * 1088 + i * 68 + og * 4];
        float4 s3 = *(const float4*)&sft[3 * 1088 + i * 68 + og * 4];
        float v0 = s0.x + s1.x + s2.x + s3.x;
        float v1 = s0.y + s1.y + s2.y + s3.y;
        float v2 = s0.z + s1.z + s2.z + s3.z;
        float v3 = s0.w + s1.w + s2.w + s3.w;
        float* ob_ = out + (b * 64 + og * 4) * 2048 + i0 + i;
        unsafeAtomicAdd(ob_ + 0 * 2048, v0);
        unsafeAtomicAdd(ob_ + 1 * 2048, v1);
        unsafeAtomicAdd(ob_ + 2 * 2048, v2);
        unsafeAtomicAdd(ob_ + 3 * 2048, v3);
    }
#undef STAGE
}

extern "C" void kernel_launch(void* const* d_in, const int* in_sizes, int n_in,
                              void* d_out, int out_size, void* d_ws, size_t ws_size,
                              hipStream_t stream)
{
    const float* locs    = (const float*)d_in[0];   // (B, N, 3)
    const float* data    = (const float*)d_in[1];   // (B, CIN, N)
    const float* density = (const float*)d_in[2];   // (B, N)
    const float* weight  = (const float*)d_in[3];   // (COUT, CIN, 9)
    const float* bias    = (const float*)d_in[4];   // (COUT,)
    float* out = (float*)d_out;                     // (B, COUT, N)

    float2*   posT = (float2*)d_ws;                             // 32768 B
    uint16_t* dC   = (uint16_t*)((char*)d_ws + 32768);          // 524288 B
    uint16_t* WB   = (uint16_t*)((char*)d_ws + 32768 + 524288); // 73728 B

    prep_kernel<<<272 + NCELL + 128, 256, 0, stream>>>(
        locs, data, density, weight, bias, posT, dC, WB, out);
    conv_kernel<<<BATCH * 128 * 4, 256, 0, stream>>>(posT, dC, WB, out);
}